// Round 15
// baseline (117.839 us; speedup 1.0000x reference)
//
#include <hip/hip_runtime.h>
#include <hip/hip_bf16.h>
#include <math.h>

#define DEVI static __device__ __forceinline__

using f32x4  = __attribute__((ext_vector_type(4))) float;
using f32x16 = __attribute__((ext_vector_type(16))) float;
using s16x8  = __attribute__((ext_vector_type(8))) short;
using bf16x8 = __attribute__((ext_vector_type(8))) __bf16;
using i32x4  = __attribute__((ext_vector_type(4))) int;
using u32x2  = __attribute__((ext_vector_type(2))) unsigned int;
using u32x4  = __attribute__((ext_vector_type(4))) unsigned int;

constexpr int N   = 8192;
constexpr int KIN = 512;
constexpr int F   = 256;

DEVI unsigned f2bf(float f) {
  unsigned u = __builtin_bit_cast(unsigned, f);
  return ((u + 0x7FFFu + ((u >> 16) & 1u)) >> 16) & 0xFFFFu;
}

DEVI float bfLO(unsigned u) { return __builtin_bit_cast(float, (u & 0xFFFFu) << 16); }
DEVI float bfHI(unsigned u) { return __builtin_bit_cast(float, u & 0xFFFF0000u); }

DEVI unsigned cvtpk(float lo, float hi) {
  unsigned r;
  asm("v_cvt_pk_bf16_f32 %0, %1, %2" : "=v"(r) : "v"(lo), "v"(hi));
  return r;
}

DEVI f32x16 mfma32(s16x8 a, s16x8 b, f32x16 c) {
  return __builtin_amdgcn_mfma_f32_32x32x16_bf16(
      __builtin_bit_cast(bf16x8, a), __builtin_bit_cast(bf16x8, b), c, 0, 0, 0);
}

DEVI void gload16(const void* g, void* lds_uniform) {
  __builtin_amdgcn_global_load_lds(
      (const __attribute__((address_space(1))) unsigned*)g,
      (__attribute__((address_space(3))) unsigned*)lds_uniform, 16, 0, 0);
}

// ---------------- cast input f32 -> bf16 (row-major [8192][512]) ----------------
__global__ __launch_bounds__(256) void k_cast(const float* __restrict__ src,
                                              unsigned short* __restrict__ dst,
                                              int n8) {
  int t = blockIdx.x * 256 + threadIdx.x;
  if (t >= n8) return;
  const f32x4* p = (const f32x4*)(src + (size_t)t * 8);
  f32x4 v0 = p[0], v1 = p[1];
  s16x8 o;
  o[0] = (short)f2bf(v0[0]); o[1] = (short)f2bf(v0[1]);
  o[2] = (short)f2bf(v0[2]); o[3] = (short)f2bf(v0[3]);
  o[4] = (short)f2bf(v1[0]); o[5] = (short)f2bf(v1[1]);
  o[6] = (short)f2bf(v1[2]); o[7] = (short)f2bf(v1[3]);
  *(s16x8*)(dst + (size_t)t * 8) = o;
}

// ---------------- W [512][256] f32 -> Wt [256][512] bf16 (transposed) -----------
__global__ __launch_bounds__(256) void k_prep_w(const float* __restrict__ W,
                                                unsigned short* __restrict__ Wt) {
  int t = blockIdx.x * 256 + threadIdx.x;   // 16384 threads
  int c = t >> 6, k0 = (t & 63) * 8;
  s16x8 o;
#pragma unroll
  for (int i = 0; i < 8; ++i) o[i] = (short)f2bf(W[(size_t)(k0 + i) * F + c]);
  *(s16x8*)(Wt + (size_t)c * KIN + k0) = o;
}

// ---------------- h = Xbf @ Wt^T : writes Ht[256][8192] bf16 + E/E5/FG ----------
__global__ __launch_bounds__(512) void k_gemm1(const unsigned short* __restrict__ inpb,
                                               const unsigned short* __restrict__ Wt,
                                               const float* __restrict__ a_vec,
                                               unsigned short* __restrict__ Ht,
                                               float* __restrict__ E, float* __restrict__ E5,
                                               unsigned* __restrict__ FG) {
  __shared__ __align__(16) char lds[4096 + 32768 + 2048];
  char* ldsA = lds;                 // [32 rows][128 B]  (XOR-swizzled)
  char* ldsW = lds + 4096;          // [256 cols][128 B] (XOR-swizzled)
  float* red = (float*)(lds + 36864); // [2][32][8]
  int tid = threadIdx.x, w = tid >> 6, l = tid & 63;
  int r0 = blockIdx.x * 32;
  f32x16 acc;
#pragma unroll
  for (int i = 0; i < 16; ++i) acc[i] = 0.f;

  int lrow8 = l >> 3;
  int koffB = ((l & 7) ^ lrow8) * 8;   // pre-swizzled source k-offset (elements)
  int ra = l & 31, kb = (l >> 5) * 8;
  int colw = w * 32 + ra;

  for (int it = 0; it < 8; ++it) {
    int k0 = it * 64;
    __syncthreads();
    if (w < 4) {
      int row = 8 * w + lrow8;
      gload16(inpb + (size_t)(r0 + row) * KIN + k0 + koffB, ldsA + w * 1024);
    }
#pragma unroll
    for (int qi = 0; qi < 4; ++qi) {
      int q = 4 * w + qi;
      int c = 8 * q + lrow8;
      gload16(Wt + (size_t)c * KIN + k0 + koffB, ldsW + q * 1024);
    }
    __syncthreads();
    s16x8 av[4], bv[4];
#pragma unroll
    for (int kf = 0; kf < 4; ++kf) {
      int kk2 = (kf * 16 + kb) * 2;
      av[kf] = *(const s16x8*)(ldsA + ra * 128 + (kk2 ^ ((ra & 7) << 4)));
      bv[kf] = *(const s16x8*)(ldsW + colw * 128 + (kk2 ^ ((colw & 7) << 4)));
    }
#pragma unroll
    for (int kf = 0; kf < 4; ++kf) acc = mfma32(av[kf], bv[kf], acc);
  }

  float a1 = a_vec[colw], a2 = a_vec[256 + colw];
  int rquad = (l >> 5) * 4;
#pragma unroll
  for (int g = 0; g < 4; ++g) {
    int rowb = g * 8 + rquad;
    unsigned h0 = f2bf(acc[g * 4 + 0]), h1 = f2bf(acc[g * 4 + 1]);
    unsigned h2 = f2bf(acc[g * 4 + 2]), h3 = f2bf(acc[g * 4 + 3]);
    u32x2 pk;
    pk[0] = h0 | (h1 << 16);
    pk[1] = h2 | (h3 << 16);
    *(u32x2*)(Ht + (size_t)colw * N + r0 + rowb) = pk;
  }
#pragma unroll
  for (int g = 0; g < 16; ++g) {
    float vs = acc[g] * a1;
    float vn = acc[g] * a2;
#pragma unroll
    for (int m = 1; m <= 16; m <<= 1) {
      vs += __shfl_xor(vs, m, 64);
      vn += __shfl_xor(vn, m, 64);
    }
    if ((l & 31) == 0) {
      int row = (g & 3) + 8 * (g >> 2) + rquad;
      red[row * 8 + w] = vs;
      red[256 + row * 8 + w] = vn;
    }
  }
  __syncthreads();
  if (tid < 32) {
    float s = 0.f, n2 = 0.f;
#pragma unroll
    for (int i = 0; i < 8; ++i) { s += red[tid * 8 + i]; n2 += red[256 + tid * 8 + i]; }
    E[r0 + tid]  = expf(s);
    E5[r0 + tid] = expf(0.2f * s);
    FG[r0 + tid] = f2bf(expf(n2)) | (f2bf(expf(0.2f * n2)) << 16);
  }
}

// ---------------- fused masked-softmax-numerator @ h: kt-split + XCD pinning ----
// R12 structure (verified passing, 114.3us) with ONE change: XCD-aware block
// swizzle. Dispatch round-robins XCD = slot&7 (m09); remap so each j-quarter
// (ks) is pinned to an XCD PAIR: ks = (slot&7)>>1, rb = (slot>>3)*2 + (slot&1)
// (bijective over 512). Each pair's 8MB aggregate L2 then holds its quarter's
// 1MB Ht slice + 32KB FG persistently -> Ht re-reads become L2 hits instead of
// L3 round-trips (Ht re-read = 512 blocks x 1MB was the dominant reuse stream).
__global__ __launch_bounds__(512, 4) void k_phase2(const int* __restrict__ adj,
                                                   const unsigned short* __restrict__ Ht,
                                                   const float* __restrict__ E,
                                                   const float* __restrict__ E5,
                                                   const unsigned* __restrict__ FG,
                                                   unsigned short* __restrict__ pacc,
                                                   float* __restrict__ ps) {
  __shared__ __align__(16) char lds[65536 + 8192];
  char* ldsH = lds;            // 2 x [256 feats][64 j] bf16, swizzled (32KB each)
  char* ldsP = lds + 65536;    // 1 x [64 rows][64 j] bf16, swizzled (8KB)

  const int tid = threadIdx.x, w = tid >> 6, l = tid & 63;
  const int slot = blockIdx.x;
  const int xcd = slot & 7;
  const int ks = xcd >> 1;                     // quarter pinned to XCD pair
  const int rb = (slot >> 3) * 2 + (xcd & 1);  // 0..127, bijective
  const int r0 = rb * 64;
  const int jb = ks * 2048;

  // producer role: thread covers row r, j = it*64 + jc8 .. +7
  const int r = tid >> 3, jc8 = (tid & 7) * 8;
  const float Er = E[r0 + r], E5r = E5[r0 + r];
  float s_part = 0.f;
  const int*      __restrict__ adjR = adj + (size_t)(r0 + r) * N + jb + jc8;
  const unsigned* __restrict__ fgR  = FG + jb + jc8;
  const int pw_byte = r * 128 + ((jc8 * 2) ^ ((r & 7) << 4));

  // staging addressing
  const int lrow8 = l >> 3;
  const int koffB = ((l & 7) ^ lrow8) * 8;

  // consumer role
  const int kh = w >> 2, fgp = (w >> 1) & 1, rg = w & 1;
  const int ra = rg * 32 + (l & 31);
  const int khb = (l >> 5) * 16;
  const int colb = fgp * 128 + (l & 31);
  const int swzA = (ra & 7) << 4;
  const int swzB = (l & 7) << 4;
  const int kt0 = kh * 2;

  f32x16 acc0, acc1, acc2, acc3;   // col-groups colb, +32, +64, +96
#pragma unroll
  for (int i = 0; i < 16; ++i) { acc0[i] = 0.f; acc1[i] = 0.f; acc2[i] = 0.f; acc3[i] = 0.f; }

  // ---- prologue: stage H(0) FIRST (so pf(0)'s auto-wait retires it), then pf(0)
#pragma unroll
  for (int qi = 0; qi < 4; ++qi) {
    int q = 4 * w + qi;
    int c = 8 * q + lrow8;
    gload16(Ht + (size_t)c * N + jb + koffB, ldsH + q * 1024);
  }
  i32x4 ad0 = *(const i32x4*)(adjR);
  i32x4 ad1 = *(const i32x4*)(adjR + 4);
  u32x4 fc0 = *(const u32x4*)(fgR);
  u32x4 fc1 = *(const u32x4*)(fgR + 4);

  for (int it = 0; it < 32; ++it) {
    char* Hc = ldsH + (it & 1) * 32768;
    char* Hn = ldsH + ((it & 1) ^ 1) * 32768;
    const int jn = ((it + 1) & 31) * 64;

    // P-gen(it): p = adj ? max(Er*F, E5r*G) : 0  (exact LeakyReLU-exp identity)
    {
      float p0 = (ad0[0] != 0) ? fmaxf(Er * bfLO(fc0[0]), E5r * bfHI(fc0[0])) : 0.f;
      float p1 = (ad0[1] != 0) ? fmaxf(Er * bfLO(fc0[1]), E5r * bfHI(fc0[1])) : 0.f;
      float p2 = (ad0[2] != 0) ? fmaxf(Er * bfLO(fc0[2]), E5r * bfHI(fc0[2])) : 0.f;
      float p3 = (ad0[3] != 0) ? fmaxf(Er * bfLO(fc0[3]), E5r * bfHI(fc0[3])) : 0.f;
      float p4 = (ad1[0] != 0) ? fmaxf(Er * bfLO(fc1[0]), E5r * bfHI(fc1[0])) : 0.f;
      float p5 = (ad1[1] != 0) ? fmaxf(Er * bfLO(fc1[1]), E5r * bfHI(fc1[1])) : 0.f;
      float p6 = (ad1[2] != 0) ? fmaxf(Er * bfLO(fc1[2]), E5r * bfHI(fc1[2])) : 0.f;
      float p7 = (ad1[3] != 0) ? fmaxf(Er * bfLO(fc1[3]), E5r * bfHI(fc1[3])) : 0.f;
      s_part += ((p0 + p1) + (p2 + p3)) + ((p4 + p5) + (p6 + p7));
      u32x4 pk;
      pk[0] = cvtpk(p0, p1); pk[1] = cvtpk(p2, p3);
      pk[2] = cvtpk(p4, p5); pk[3] = cvtpk(p6, p7);
      *(u32x4*)(ldsP + pw_byte) = pk;
    }

    // pf(it+1) into the now-dead registers
    ad0 = *(const i32x4*)(adjR + jn);
    ad1 = *(const i32x4*)(adjR + jn + 4);
    fc0 = *(const u32x4*)(fgR + jn);
    fc1 = *(const u32x4*)(fgR + jn + 4);

    // retire stage(it) [older than pf(it+1) in FIFO]; P write visible
    asm volatile("s_waitcnt vmcnt(4) lgkmcnt(0)" ::: "memory");
    __builtin_amdgcn_s_barrier();

    // stage H(it+1) into Hn (its readers drained at the previous barrier)
#pragma unroll
    for (int qi = 0; qi < 4; ++qi) {
      int q = 4 * w + qi;
      int c = 8 * q + lrow8;
      gload16(Ht + (size_t)c * N + jb + jn + koffB, Hn + q * 1024);
    }

    // consume: this wave's 2 k-steps x 4 col-groups
#pragma unroll
    for (int t2 = 0; t2 < 2; ++t2) {
      int kk2 = (kt0 + t2) * 32 + khb;
      s16x8 av = *(const s16x8*)(ldsP + ra * 128 + (kk2 ^ swzA));
      s16x8 b0 = *(const s16x8*)(Hc + (colb     ) * 128 + (kk2 ^ swzB));
      s16x8 b1 = *(const s16x8*)(Hc + (colb + 32) * 128 + (kk2 ^ swzB));
      s16x8 b2 = *(const s16x8*)(Hc + (colb + 64) * 128 + (kk2 ^ swzB));
      s16x8 b3 = *(const s16x8*)(Hc + (colb + 96) * 128 + (kk2 ^ swzB));
      acc0 = mfma32(av, b0, acc0);
      acc1 = mfma32(av, b1, acc1);
      acc2 = mfma32(av, b2, acc2);
      acc3 = mfma32(av, b3, acc3);
    }

    // all P/Hc reads complete before next produce overwrites P
    asm volatile("s_waitcnt lgkmcnt(0)" ::: "memory");
    __builtin_amdgcn_s_barrier();
  }

  // ---- epilogue ----
  // partial rowsum (8 threads/row)
  float s = s_part;
#pragma unroll
  for (int m = 1; m <= 4; m <<= 1) s += __shfl_xor(s, m, 64);
  if ((tid & 7) == 0) ps[(size_t)ks * N + r0 + r] = s;

  // kh-pair acc merge via LDS (waves w and w+4 share (row,col) tile)
  __syncthreads();   // drain wrapped stage writes before reusing ldsH
  float* red = (float*)ldsH;                 // 64 KB scratch
  const int rbase = (fgp * 2 + rg) * 4096;   // floats
  if (kh == 1) {
#pragma unroll
    for (int cg = 0; cg < 4; ++cg) {
      const f32x16* a = (cg == 0) ? &acc0 : (cg == 1) ? &acc1 : (cg == 2) ? &acc2 : &acc3;
#pragma unroll
      for (int q = 0; q < 4; ++q) {
        f32x4 v;
#pragma unroll
        for (int i = 0; i < 4; ++i) v[i] = (*a)[q * 4 + i];
        int boff = (cg * 64 + q * 16) ^ ((l & 7) << 4);   // bank-spread
        *(f32x4*)((char*)&red[rbase + l * 64] + boff) = v;
      }
    }
  }
  __syncthreads();
  if (kh == 0) {
#pragma unroll
    for (int cg = 0; cg < 4; ++cg) {
      f32x16* a = (cg == 0) ? &acc0 : (cg == 1) ? &acc1 : (cg == 2) ? &acc2 : &acc3;
#pragma unroll
      for (int q = 0; q < 4; ++q) {
        int boff = (cg * 64 + q * 16) ^ ((l & 7) << 4);
        f32x4 v = *(const f32x4*)((const char*)&red[rbase + l * 64] + boff);
#pragma unroll
        for (int i = 0; i < 4; ++i) (*a)[q * 4 + i] += v[i];
      }
    }
    unsigned short* po = pacc + (size_t)ks * N * F;
#pragma unroll
    for (int g = 0; g < 16; ++g) {
      int orow = rg * 32 + (g & 3) + 8 * (g >> 2) + 4 * (l >> 5);
      unsigned short* pr = po + (size_t)(r0 + orow) * F + colb;
      pr[0]  = (unsigned short)f2bf(acc0[g]);
      pr[32] = (unsigned short)f2bf(acc1[g]);
      pr[64] = (unsigned short)f2bf(acc2[g]);
      pr[96] = (unsigned short)f2bf(acc3[g]);
    }
  }
}

// ---------------- combine 4 bf16 split-K partials, normalize, ELU ---------------
__global__ __launch_bounds__(256) void k_combine(const unsigned short* __restrict__ pacc,
                                                 const float* __restrict__ ps,
                                                 float* __restrict__ out) {
  int t = blockIdx.x * 256 + threadIdx.x;  // 524288 threads, 4 feats each
  size_t idx = (size_t)t * 4;
  int row = (int)(idx >> 8);
  f32x4 sum;
#pragma unroll
  for (int i = 0; i < 4; ++i) sum[i] = 0.f;
#pragma unroll
  for (int k = 0; k < 4; ++k) {
    u32x2 q = *(const u32x2*)(pacc + (size_t)k * N * F + idx);
    sum[0] += bfLO(q[0]); sum[1] += bfHI(q[0]);
    sum[2] += bfLO(q[1]); sum[3] += bfHI(q[1]);
  }
  float inv = 1.f / (ps[row] + ps[N + row] + ps[2 * N + row] + ps[3 * N + row]);
  f32x4 o;
#pragma unroll
  for (int i = 0; i < 4; ++i) {
    float v = sum[i] * inv;
    o[i] = v > 0.f ? v : expm1f(v);
  }
  *(f32x4*)(out + idx) = o;
}

extern "C" void kernel_launch(void* const* d_in, const int* in_sizes, int n_in,
                              void* d_out, int out_size, void* d_ws, size_t ws_size,
                              hipStream_t stream) {
  const float* input = (const float*)d_in[0];
  const int*   adj   = (const int*)d_in[1];
  const float* W     = (const float*)d_in[2];
  const float* a     = (const float*)d_in[3];
  float* out = (float*)d_out;
  char* ws = (char*)d_ws;

  // pacc (16 MB, bf16) aliases inpb+Wt: both dead before k_phase2 runs.
  unsigned short* pacc = (unsigned short*)(ws);              // 16,777,216 B @0
  unsigned short* inpb = (unsigned short*)(ws);              //  8,388,608 B @0
  unsigned short* Wt   = (unsigned short*)(ws + 8388608);    //    262,144 B
  unsigned short* Ht   = (unsigned short*)(ws + 16777216);   //  4,194,304 B
  float*    E  = (float*)(ws + 20971520);                    //     32,768 B
  float*    E5 = (float*)(ws + 21004288);                    //     32,768 B
  unsigned* FG = (unsigned*)(ws + 21037056);                 //     32,768 B
  float*    ps = (float*)(ws + 21069824);                    //    131,072 B -> 21.2 MB

  hipLaunchKernelGGL(k_cast,   dim3(2048), dim3(256), 0, stream, input, inpb, 524288);
  hipLaunchKernelGGL(k_prep_w, dim3(64),   dim3(256), 0, stream, W, Wt);
  hipLaunchKernelGGL(k_gemm1,  dim3(256),  dim3(512), 0, stream, inpb, Wt, a, Ht, E, E5, FG);
  hipLaunchKernelGGL(k_phase2, dim3(512),  dim3(512), 0, stream, adj, Ht, E, E5, FG, pacc, ps);
  hipLaunchKernelGGL(k_combine,dim3(2048), dim3(256), 0, stream, pacc, ps, out);
}

// Round 16
// 112.362 us; speedup vs baseline: 1.0487x; 1.0487x over previous
//
#include <hip/hip_runtime.h>
#include <hip/hip_bf16.h>
#include <math.h>

#define DEVI static __device__ __forceinline__

using f32x4  = __attribute__((ext_vector_type(4))) float;
using f32x16 = __attribute__((ext_vector_type(16))) float;
using s16x8  = __attribute__((ext_vector_type(8))) short;
using bf16x8 = __attribute__((ext_vector_type(8))) __bf16;
using i32x4  = __attribute__((ext_vector_type(4))) int;
using u32x2  = __attribute__((ext_vector_type(2))) unsigned int;
using u32x4  = __attribute__((ext_vector_type(4))) unsigned int;

constexpr int N   = 8192;
constexpr int KIN = 512;
constexpr int F   = 256;

DEVI unsigned f2bf(float f) {
  unsigned u = __builtin_bit_cast(unsigned, f);
  return ((u + 0x7FFFu + ((u >> 16) & 1u)) >> 16) & 0xFFFFu;
}

DEVI float bfLO(unsigned u) { return __builtin_bit_cast(float, (u & 0xFFFFu) << 16); }
DEVI float bfHI(unsigned u) { return __builtin_bit_cast(float, u & 0xFFFF0000u); }

DEVI unsigned cvtpk(float lo, float hi) {
  unsigned r;
  asm("v_cvt_pk_bf16_f32 %0, %1, %2" : "=v"(r) : "v"(lo), "v"(hi));
  return r;
}

DEVI f32x16 mfma32(s16x8 a, s16x8 b, f32x16 c) {
  return __builtin_amdgcn_mfma_f32_32x32x16_bf16(
      __builtin_bit_cast(bf16x8, a), __builtin_bit_cast(bf16x8, b), c, 0, 0, 0);
}

DEVI void gload16(const void* g, void* lds_uniform) {
  __builtin_amdgcn_global_load_lds(
      (const __attribute__((address_space(1))) unsigned*)g,
      (__attribute__((address_space(3))) unsigned*)lds_uniform, 16, 0, 0);
}

// ---------------- W [512][256] f32 -> Wt [256][512] bf16 (transposed) -----------
__global__ __launch_bounds__(256) void k_prep_w(const float* __restrict__ W,
                                                unsigned short* __restrict__ Wt) {
  int t = blockIdx.x * 256 + threadIdx.x;   // 16384 threads
  int c = t >> 6, k0 = (t & 63) * 8;
  s16x8 o;
#pragma unroll
  for (int i = 0; i < 8; ++i) o[i] = (short)f2bf(W[(size_t)(k0 + i) * F + c]);
  *(s16x8*)(Wt + (size_t)c * KIN + k0) = o;
}

// ---------------- h = X @ Wt^T (cast fused) : Ht[256][8192] bf16 + E/E5/FG ------
// A staged as raw f32 via global_load_lds (8KB tile, source elem offset
// pre-swizzled by (row&7)<<2 so the swizzled 16B-granular read below recovers
// linear elements); converted to bf16 fragments in-register with
// v_cvt_pk_bf16_f32 (RNE - bit-identical to the old k_cast+bf16-load path).
__global__ __launch_bounds__(512) void k_gemm1(const float* __restrict__ input,
                                               const unsigned short* __restrict__ Wt,
                                               const float* __restrict__ a_vec,
                                               unsigned short* __restrict__ Ht,
                                               float* __restrict__ E, float* __restrict__ E5,
                                               unsigned* __restrict__ FG) {
  __shared__ __align__(16) char lds[8192 + 32768 + 2048];
  char* ldsA = lds;                 // [32 rows][256 B] f32 (16B-unit XOR-swizzled)
  char* ldsW = lds + 8192;          // [256 cols][128 B] bf16 (XOR-swizzled)
  float* red = (float*)(lds + 8192 + 32768); // [2][32][8]
  int tid = threadIdx.x, w = tid >> 6, l = tid & 63;
  int r0 = blockIdx.x * 32;
  f32x16 acc;
#pragma unroll
  for (int i = 0; i < 16; ++i) acc[i] = 0.f;

  int lrow8 = l >> 3;
  int koffB = ((l & 7) ^ lrow8) * 8;   // pre-swizzled source k-offset (bf16 elems)
  int ra = l & 31, kb = (l >> 5) * 8;
  int colw = w * 32 + ra;

  // A staging role: thread covers row arow, 16B chunk ac16 (4 f32)
  const int arow = tid >> 4, ac16 = tid & 15;
  const int aoff = (ac16 * 4) ^ ((arow & 7) << 2);   // pre-swizzled f32 elem off
  const float* aR = input + (size_t)(r0 + arow) * KIN + aoff;

  for (int it = 0; it < 8; ++it) {
    int k0 = it * 64;
    __syncthreads();
    // stage A (f32, 8KB): 512 threads x 16B; LDS dest linear = tid*16
    gload16(aR + k0, ldsA + w * 1024);
    // stage W (bf16, 32KB)
#pragma unroll
    for (int qi = 0; qi < 4; ++qi) {
      int q = 4 * w + qi;
      int c = 8 * q + lrow8;
      gload16(Wt + (size_t)c * KIN + k0 + koffB, ldsW + q * 1024);
    }
    __syncthreads();
    s16x8 av[4], bv[4];
#pragma unroll
    for (int kf = 0; kf < 4; ++kf) {
      int e4 = (kf * 16 + kb) * 4;        // byte offset of fragment (32B-aligned)
      f32x4 a0 = *(const f32x4*)(ldsA + ra * 256 + (e4 ^ ((ra & 7) << 4)));
      f32x4 a1 = *(const f32x4*)(ldsA + ra * 256 + ((e4 + 16) ^ ((ra & 7) << 4)));
      u32x4 ap;
      ap[0] = cvtpk(a0[0], a0[1]); ap[1] = cvtpk(a0[2], a0[3]);
      ap[2] = cvtpk(a1[0], a1[1]); ap[3] = cvtpk(a1[2], a1[3]);
      av[kf] = __builtin_bit_cast(s16x8, ap);
      int kk2 = (kf * 16 + kb) * 2;
      bv[kf] = *(const s16x8*)(ldsW + colw * 128 + (kk2 ^ ((colw & 7) << 4)));
    }
#pragma unroll
    for (int kf = 0; kf < 4; ++kf) acc = mfma32(av[kf], bv[kf], acc);
  }

  float a1v = a_vec[colw], a2v = a_vec[256 + colw];
  int rquad = (l >> 5) * 4;
#pragma unroll
  for (int g = 0; g < 4; ++g) {
    int rowb = g * 8 + rquad;
    unsigned h0 = f2bf(acc[g * 4 + 0]), h1 = f2bf(acc[g * 4 + 1]);
    unsigned h2 = f2bf(acc[g * 4 + 2]), h3 = f2bf(acc[g * 4 + 3]);
    u32x2 pk;
    pk[0] = h0 | (h1 << 16);
    pk[1] = h2 | (h3 << 16);
    *(u32x2*)(Ht + (size_t)colw * N + r0 + rowb) = pk;
  }
#pragma unroll
  for (int g = 0; g < 16; ++g) {
    float vs = acc[g] * a1v;
    float vn = acc[g] * a2v;
#pragma unroll
    for (int m = 1; m <= 16; m <<= 1) {
      vs += __shfl_xor(vs, m, 64);
      vn += __shfl_xor(vn, m, 64);
    }
    if ((l & 31) == 0) {
      int row = (g & 3) + 8 * (g >> 2) + rquad;
      red[row * 8 + w] = vs;
      red[256 + row * 8 + w] = vn;
    }
  }
  __syncthreads();
  if (tid < 32) {
    float s = 0.f, n2 = 0.f;
#pragma unroll
    for (int i = 0; i < 8; ++i) { s += red[tid * 8 + i]; n2 += red[256 + tid * 8 + i]; }
    E[r0 + tid]  = expf(s);
    E5[r0 + tid] = expf(0.2f * s);
    FG[r0 + tid] = f2bf(expf(n2)) | (f2bf(expf(0.2f * n2)) << 16);
  }
}

// ---------------- fused masked-softmax-numerator @ h: kt-split (R12, verified) --
// grid 512 = 128 row-blocks (64 rows) x KSPLIT=4; 512 threads; 2 blocks/CU
// (LDS 72KB, regs <=128 via launch_bounds(512,4)). Wave role: w = kh*4+fgp*2+rg.
// Per wave-iter: 2 A + 8 B ds_reads -> 8 MFMA. Byte-identical to R12 (114.3us,
// absmax 0.0078) - the verified best phase2.
__global__ __launch_bounds__(512, 4) void k_phase2(const int* __restrict__ adj,
                                                   const unsigned short* __restrict__ Ht,
                                                   const float* __restrict__ E,
                                                   const float* __restrict__ E5,
                                                   const unsigned* __restrict__ FG,
                                                   unsigned short* __restrict__ pacc,
                                                   float* __restrict__ ps) {
  __shared__ __align__(16) char lds[65536 + 8192];
  char* ldsH = lds;            // 2 x [256 feats][64 j] bf16, swizzled (32KB each)
  char* ldsP = lds + 65536;    // 1 x [64 rows][64 j] bf16, swizzled (8KB)

  const int tid = threadIdx.x, w = tid >> 6, l = tid & 63;
  const int rb = blockIdx.x >> 2, ks = blockIdx.x & 3;
  const int r0 = rb * 64;
  const int jb = ks * 2048;

  const int r = tid >> 3, jc8 = (tid & 7) * 8;
  const float Er = E[r0 + r], E5r = E5[r0 + r];
  float s_part = 0.f;
  const int*      __restrict__ adjR = adj + (size_t)(r0 + r) * N + jb + jc8;
  const unsigned* __restrict__ fgR  = FG + jb + jc8;
  const int pw_byte = r * 128 + ((jc8 * 2) ^ ((r & 7) << 4));

  const int lrow8 = l >> 3;
  const int koffB = ((l & 7) ^ lrow8) * 8;

  const int kh = w >> 2, fgp = (w >> 1) & 1, rg = w & 1;
  const int ra = rg * 32 + (l & 31);
  const int khb = (l >> 5) * 16;
  const int colb = fgp * 128 + (l & 31);
  const int swzA = (ra & 7) << 4;
  const int swzB = (l & 7) << 4;
  const int kt0 = kh * 2;

  f32x16 acc0, acc1, acc2, acc3;
#pragma unroll
  for (int i = 0; i < 16; ++i) { acc0[i] = 0.f; acc1[i] = 0.f; acc2[i] = 0.f; acc3[i] = 0.f; }

#pragma unroll
  for (int qi = 0; qi < 4; ++qi) {
    int q = 4 * w + qi;
    int c = 8 * q + lrow8;
    gload16(Ht + (size_t)c * N + jb + koffB, ldsH + q * 1024);
  }
  i32x4 ad0 = *(const i32x4*)(adjR);
  i32x4 ad1 = *(const i32x4*)(adjR + 4);
  u32x4 fc0 = *(const u32x4*)(fgR);
  u32x4 fc1 = *(const u32x4*)(fgR + 4);

  for (int it = 0; it < 32; ++it) {
    char* Hc = ldsH + (it & 1) * 32768;
    char* Hn = ldsH + ((it & 1) ^ 1) * 32768;
    const int jn = ((it + 1) & 31) * 64;

    {
      float p0 = (ad0[0] != 0) ? fmaxf(Er * bfLO(fc0[0]), E5r * bfHI(fc0[0])) : 0.f;
      float p1 = (ad0[1] != 0) ? fmaxf(Er * bfLO(fc0[1]), E5r * bfHI(fc0[1])) : 0.f;
      float p2 = (ad0[2] != 0) ? fmaxf(Er * bfLO(fc0[2]), E5r * bfHI(fc0[2])) : 0.f;
      float p3 = (ad0[3] != 0) ? fmaxf(Er * bfLO(fc0[3]), E5r * bfHI(fc0[3])) : 0.f;
      float p4 = (ad1[0] != 0) ? fmaxf(Er * bfLO(fc1[0]), E5r * bfHI(fc1[0])) : 0.f;
      float p5 = (ad1[1] != 0) ? fmaxf(Er * bfLO(fc1[1]), E5r * bfHI(fc1[1])) : 0.f;
      float p6 = (ad1[2] != 0) ? fmaxf(Er * bfLO(fc1[2]), E5r * bfHI(fc1[2])) : 0.f;
      float p7 = (ad1[3] != 0) ? fmaxf(Er * bfLO(fc1[3]), E5r * bfHI(fc1[3])) : 0.f;
      s_part += ((p0 + p1) + (p2 + p3)) + ((p4 + p5) + (p6 + p7));
      u32x4 pk;
      pk[0] = cvtpk(p0, p1); pk[1] = cvtpk(p2, p3);
      pk[2] = cvtpk(p4, p5); pk[3] = cvtpk(p6, p7);
      *(u32x4*)(ldsP + pw_byte) = pk;
    }

    ad0 = *(const i32x4*)(adjR + jn);
    ad1 = *(const i32x4*)(adjR + jn + 4);
    fc0 = *(const u32x4*)(fgR + jn);
    fc1 = *(const u32x4*)(fgR + jn + 4);

    asm volatile("s_waitcnt vmcnt(4) lgkmcnt(0)" ::: "memory");
    __builtin_amdgcn_s_barrier();

#pragma unroll
    for (int qi = 0; qi < 4; ++qi) {
      int q = 4 * w + qi;
      int c = 8 * q + lrow8;
      gload16(Ht + (size_t)c * N + jb + jn + koffB, Hn + q * 1024);
    }

#pragma unroll
    for (int t2 = 0; t2 < 2; ++t2) {
      int kk2 = (kt0 + t2) * 32 + khb;
      s16x8 av = *(const s16x8*)(ldsP + ra * 128 + (kk2 ^ swzA));
      s16x8 b0 = *(const s16x8*)(Hc + (colb     ) * 128 + (kk2 ^ swzB));
      s16x8 b1 = *(const s16x8*)(Hc + (colb + 32) * 128 + (kk2 ^ swzB));
      s16x8 b2 = *(const s16x8*)(Hc + (colb + 64) * 128 + (kk2 ^ swzB));
      s16x8 b3 = *(const s16x8*)(Hc + (colb + 96) * 128 + (kk2 ^ swzB));
      acc0 = mfma32(av, b0, acc0);
      acc1 = mfma32(av, b1, acc1);
      acc2 = mfma32(av, b2, acc2);
      acc3 = mfma32(av, b3, acc3);
    }

    asm volatile("s_waitcnt lgkmcnt(0)" ::: "memory");
    __builtin_amdgcn_s_barrier();
  }

  float s = s_part;
#pragma unroll
  for (int m = 1; m <= 4; m <<= 1) s += __shfl_xor(s, m, 64);
  if ((tid & 7) == 0) ps[(size_t)ks * N + r0 + r] = s;

  __syncthreads();
  float* red = (float*)ldsH;
  const int rbase = (fgp * 2 + rg) * 4096;
  if (kh == 1) {
#pragma unroll
    for (int cg = 0; cg < 4; ++cg) {
      const f32x16* a = (cg == 0) ? &acc0 : (cg == 1) ? &acc1 : (cg == 2) ? &acc2 : &acc3;
#pragma unroll
      for (int q = 0; q < 4; ++q) {
        f32x4 v;
#pragma unroll
        for (int i = 0; i < 4; ++i) v[i] = (*a)[q * 4 + i];
        int boff = (cg * 64 + q * 16) ^ ((l & 7) << 4);
        *(f32x4*)((char*)&red[rbase + l * 64] + boff) = v;
      }
    }
  }
  __syncthreads();
  if (kh == 0) {
#pragma unroll
    for (int cg = 0; cg < 4; ++cg) {
      f32x16* a = (cg == 0) ? &acc0 : (cg == 1) ? &acc1 : (cg == 2) ? &acc2 : &acc3;
#pragma unroll
      for (int q = 0; q < 4; ++q) {
        int boff = (cg * 64 + q * 16) ^ ((l & 7) << 4);
        f32x4 v = *(const f32x4*)((const char*)&red[rbase + l * 64] + boff);
#pragma unroll
        for (int i = 0; i < 4; ++i) (*a)[q * 4 + i] += v[i];
      }
    }
    unsigned short* po = pacc + (size_t)ks * N * F;
#pragma unroll
    for (int g = 0; g < 16; ++g) {
      int orow = rg * 32 + (g & 3) + 8 * (g >> 2) + 4 * (l >> 5);
      unsigned short* pr = po + (size_t)(r0 + orow) * F + colb;
      pr[0]  = (unsigned short)f2bf(acc0[g]);
      pr[32] = (unsigned short)f2bf(acc1[g]);
      pr[64] = (unsigned short)f2bf(acc2[g]);
      pr[96] = (unsigned short)f2bf(acc3[g]);
    }
  }
}

// ---------------- combine 4 bf16 split-K partials, normalize, ELU ---------------
__global__ __launch_bounds__(256) void k_combine(const unsigned short* __restrict__ pacc,
                                                 const float* __restrict__ ps,
                                                 float* __restrict__ out) {
  int t = blockIdx.x * 256 + threadIdx.x;  // 524288 threads, 4 feats each
  size_t idx = (size_t)t * 4;
  int row = (int)(idx >> 8);
  f32x4 sum;
#pragma unroll
  for (int i = 0; i < 4; ++i) sum[i] = 0.f;
#pragma unroll
  for (int k = 0; k < 4; ++k) {
    u32x2 q = *(const u32x2*)(pacc + (size_t)k * N * F + idx);
    sum[0] += bfLO(q[0]); sum[1] += bfHI(q[0]);
    sum[2] += bfLO(q[1]); sum[3] += bfHI(q[1]);
  }
  float inv = 1.f / (ps[row] + ps[N + row] + ps[2 * N + row] + ps[3 * N + row]);
  f32x4 o;
#pragma unroll
  for (int i = 0; i < 4; ++i) {
    float v = sum[i] * inv;
    o[i] = v > 0.f ? v : expm1f(v);
  }
  *(f32x4*)(out + idx) = o;
}

extern "C" void kernel_launch(void* const* d_in, const int* in_sizes, int n_in,
                              void* d_out, int out_size, void* d_ws, size_t ws_size,
                              hipStream_t stream) {
  const float* input = (const float*)d_in[0];
  const int*   adj   = (const int*)d_in[1];
  const float* W     = (const float*)d_in[2];
  const float* a     = (const float*)d_in[3];
  float* out = (float*)d_out;
  char* ws = (char*)d_ws;

  // pacc (16 MB, bf16) aliases Wt (dead before k_phase2 runs).
  unsigned short* pacc = (unsigned short*)(ws);              // 16,777,216 B @0
  unsigned short* Wt   = (unsigned short*)(ws + 8388608);    //    262,144 B
  unsigned short* Ht   = (unsigned short*)(ws + 16777216);   //  4,194,304 B
  float*    E  = (float*)(ws + 20971520);                    //     32,768 B
  float*    E5 = (float*)(ws + 21004288);                    //     32,768 B
  unsigned* FG = (unsigned*)(ws + 21037056);                 //     32,768 B
  float*    ps = (float*)(ws + 21069824);                    //    131,072 B -> 21.2 MB

  hipLaunchKernelGGL(k_prep_w, dim3(64),   dim3(256), 0, stream, W, Wt);
  hipLaunchKernelGGL(k_gemm1,  dim3(256),  dim3(512), 0, stream, input, Wt, a, Ht, E, E5, FG);
  hipLaunchKernelGGL(k_phase2, dim3(512),  dim3(512), 0, stream, adj, Ht, E, E5, FG, pacc, ps);
  hipLaunchKernelGGL(k_combine,dim3(2048), dim3(256), 0, stream, pacc, ps, out);
}